// Round 9
// baseline (179.298 us; speedup 1.0000x reference)
//
#include <hip/hip_runtime.h>
#include <stdint.h>

#define Bn 256
#define Tn 50
#define Mn 20
#define En 128
#define G3 384
#define MT 64
#define LDA 132

__device__ __forceinline__ float sigmoidf(float x) {
    return 1.0f / (1.0f + __expf(-x));
}
__device__ __forceinline__ float tanh_safe(float a) {
    float ax = fabsf(a);
    float e2 = __expf(-2.0f * ax);
    return copysignf((1.0f - e2) / (1.0f + e2), a);
}

// ---------------------------------------------------------------------------
// Kernel 1: basket-mean gather -> ub [B*T][128]  (stored in d_out region)
// ---------------------------------------------------------------------------
__global__ __launch_bounds__(256) void gather_kernel(
    const int*   __restrict__ item_ids,
    const int*   __restrict__ basket_sizes,
    const float* __restrict__ emb,
    float* __restrict__ ub)
{
    const int bt   = blockIdx.x * 8 + (threadIdx.x >> 5);
    const int lane = threadIdx.x & 31;
    const int* ids = item_ids + (size_t)bt * Mn;
    float ax = 0.f, ay = 0.f, az = 0.f, aw = 0.f;
    #pragma unroll
    for (int m = 0; m < Mn; ++m) {
        const float4 v = *(const float4*)(emb + (size_t)ids[m] * En + lane * 4);
        ax += v.x; ay += v.y; az += v.z; aw += v.w;
    }
    const float inv = 1.0f / (float)basket_sizes[bt];
    *(float4*)(ub + (size_t)bt * En + lane * 4) =
        make_float4(ax * inv, ay * inv, az * inv, aw * inv);
}

// ---------------------------------------------------------------------------
// Kernel 2: xg = ub @ W_ih^T + b_ih.  1200 blocks (200 M x 6 N); 4x4 tile.
// ---------------------------------------------------------------------------
__global__ __launch_bounds__(256, 2) void gemm_kernel(
    const float* __restrict__ ub,
    const float* __restrict__ W_ih,
    const float* __restrict__ b_ih,
    float* __restrict__ xg)
{
    __shared__ float A[MT][LDA];
    __shared__ float Bt[64][LDA];

    const int tid  = threadIdx.x;
    const int mt   = blockIdx.x / 6;
    const int nc   = blockIdx.x % 6;
    const int row0 = mt * MT;
    const int col0 = nc * 64;

    {
        const int r = tid >> 2, seg = tid & 3;
        const float4* srcA = (const float4*)(ub + (size_t)(row0 + r) * En + seg * 32);
        const float4* srcB = (const float4*)(W_ih + (size_t)(col0 + r) * En + seg * 32);
        float4* dstA = (float4*)&A[r][seg * 32];
        float4* dstB = (float4*)&Bt[r][seg * 32];
        #pragma unroll
        for (int c = 0; c < 8; ++c) { dstA[c] = srcA[c]; dstB[c] = srcB[c]; }
    }
    __syncthreads();

    const int tx = tid & 15;
    const int ty = tid >> 4;

    float acc[4][4];
    #pragma unroll
    for (int i = 0; i < 4; ++i)
        #pragma unroll
        for (int u = 0; u < 4; ++u) acc[i][u] = 0.0f;

    #pragma unroll 4
    for (int k4 = 0; k4 < 32; ++k4) {
        const float4 av[4] = {
            *(const float4*)&A[ty +  0][k4*4], *(const float4*)&A[ty + 16][k4*4],
            *(const float4*)&A[ty + 32][k4*4], *(const float4*)&A[ty + 48][k4*4]};
        const float4 bv[4] = {
            *(const float4*)&Bt[tx +  0][k4*4], *(const float4*)&Bt[tx + 16][k4*4],
            *(const float4*)&Bt[tx + 32][k4*4], *(const float4*)&Bt[tx + 48][k4*4]};
        #pragma unroll
        for (int i = 0; i < 4; ++i)
            #pragma unroll
            for (int u = 0; u < 4; ++u) {
                acc[i][u] = fmaf(av[i].x, bv[u].x, acc[i][u]);
                acc[i][u] = fmaf(av[i].y, bv[u].y, acc[i][u]);
                acc[i][u] = fmaf(av[i].z, bv[u].z, acc[i][u]);
                acc[i][u] = fmaf(av[i].w, bv[u].w, acc[i][u]);
            }
    }

    float bias[4];
    #pragma unroll
    for (int u = 0; u < 4; ++u) bias[u] = b_ih[col0 + tx + 16*u];
    #pragma unroll
    for (int i = 0; i < 4; ++i) {
        const size_t rowoff = (size_t)(row0 + ty + 16*i) * G3;
        #pragma unroll
        for (int u = 0; u < 4; ++u)
            xg[rowoff + col0 + tx + 16*u] = acc[i][u] + bias[u];
    }
}

// ---------------------------------------------------------------------------
// Kernel 3: sequential GRU. 256 blocks x 1024 threads.
// Thread (j in [0,128), q in [0,8)) holds 3 gate-row slices of 16 cols = 12
// float4 of W_hh, loaded via asm volatile global_load_dwordx4 so the compiler
// CANNOT rematerialize/sink them into the step loop (plain loads were sunk in
// R4-R7). amdgpu_waves_per_eu(4,4) pins 1 block/CU -> 128-VGPR budget.
// Ordering: 12 volatile loads, then volatile s_waitcnt (volatile asms keep
// program order), then __syncthreads() before any use -> data is valid.
// ---------------------------------------------------------------------------
#define LOADP(dst, ptr) \
    asm volatile("global_load_dwordx4 %0, %1, off" : "=&v"(dst) : "v"(ptr))
#define DOT4(acc, wv, hv) \
    acc = fmaf(wv.x, hv.x, acc); acc = fmaf(wv.y, hv.y, acc); \
    acc = fmaf(wv.z, hv.z, acc); acc = fmaf(wv.w, hv.w, acc)

__global__ __launch_bounds__(1024)
__attribute__((amdgpu_waves_per_eu(4, 4)))
void gru_kernel(
    const int*   __restrict__ lengths,
    const float* __restrict__ W_hh,
    const float* __restrict__ b_hh,
    const float* __restrict__ h0,
    const float* __restrict__ xg,
    float* __restrict__ out_dyn,
    float* __restrict__ out_h)
{
    __shared__ float hs[En];
    __shared__ float red[8][3][En];   // [q][gate][j], 12 KB

    const int tid = threadIdx.x;
    const int b   = blockIdx.x;
    const int j   = tid & 127;
    const int q   = tid >> 7;         // [0,8), wave-uniform

    // gate g row g*128+j, cols [q*16, q*16+16): 12 float4, pinned in VGPRs
    float4 w00, w01, w02, w03, w10, w11, w12, w13, w20, w21, w22, w23;
    {
        const float4* p0 = (const float4*)(W_hh + (size_t)(0*En + j) * En + q * 16);
        const float4* p1 = (const float4*)(W_hh + (size_t)(1*En + j) * En + q * 16);
        const float4* p2 = (const float4*)(W_hh + (size_t)(2*En + j) * En + q * 16);
        LOADP(w00, p0+0); LOADP(w01, p0+1); LOADP(w02, p0+2); LOADP(w03, p0+3);
        LOADP(w10, p1+0); LOADP(w11, p1+1); LOADP(w12, p1+2); LOADP(w13, p1+3);
        LOADP(w20, p2+0); LOADP(w21, p2+1); LOADP(w22, p2+2); LOADP(w23, p2+3);
        asm volatile("s_waitcnt vmcnt(0)" ::: "memory");
    }

    const int len = lengths[b];
    const float* xgb = xg + (size_t)b * Tn * G3;
    float* outb = out_dyn + (size_t)b * Tn * En;

    float xr = 0.f, xz = 0.f, xn = 0.f, br = 0.f, bz = 0.f, bn = 0.f;
    if (tid < En) {
        hs[tid] = h0[(size_t)b * En + tid];
        br = b_hh[tid]; bz = b_hh[En + tid]; bn = b_hh[2*En + tid];
        xr = xgb[tid];  xz = xgb[En + tid]; xn = xgb[2*En + tid];
    }
    __syncthreads();

    for (int t = 0; t < len; ++t) {
        // phase A: partial dots over this thread's 16-col K-slice.
        // h-reads are wave-uniform addresses -> LDS broadcast.
        const float4* h4 = ((const float4*)hs) + q * 4;
        const float4 h0v = h4[0], h1v = h4[1], h2v = h4[2], h3v = h4[3];
        float a0 = 0.f, a1 = 0.f, a2 = 0.f;
        DOT4(a0, w00, h0v); DOT4(a0, w01, h1v); DOT4(a0, w02, h2v); DOT4(a0, w03, h3v);
        DOT4(a1, w10, h0v); DOT4(a1, w11, h1v); DOT4(a1, w12, h2v); DOT4(a1, w13, h3v);
        DOT4(a2, w20, h0v); DOT4(a2, w21, h1v); DOT4(a2, w22, h2v); DOT4(a2, w23, h3v);
        red[q][0][j] = a0; red[q][1][j] = a1; red[q][2][j] = a2;

        // prefetch next step's xg (overlaps barrier + phase B)
        float nxr = 0.f, nxz = 0.f, nxn = 0.f;
        if (tid < En) {
            const int tn = (t + 1 < len) ? t + 1 : t;
            nxr = xgb[tn*G3 + tid];
            nxz = xgb[tn*G3 + En + tid];
            nxn = xgb[tn*G3 + 2*En + tid];
        }
        __syncthreads();

        // phase B: reduce K-partials + gates (first 2 waves)
        if (tid < En) {
            float ar = red[0][0][tid], az = red[0][1][tid], an = red[0][2][tid];
            #pragma unroll
            for (int p = 1; p < 8; ++p) {
                ar += red[p][0][tid]; az += red[p][1][tid]; an += red[p][2][tid];
            }
            const float r = sigmoidf(xr + br + ar);
            const float z = sigmoidf(xz + bz + az);
            const float n = tanh_safe(xn + r * (bn + an));
            const float hnew = (1.0f - z) * n + z * hs[tid];
            hs[tid] = hnew;
            outb[t*En + tid] = hnew;
            xr = nxr; xz = nxz; xn = nxn;
        }
        __syncthreads();
    }

    if (tid < En) {
        for (int t = len; t < Tn; ++t) outb[t*En + tid] = 0.0f;
        out_h[(size_t)b * En + tid] = hs[tid];
    }
}

extern "C" void kernel_launch(void* const* d_in, const int* in_sizes, int n_in,
                              void* d_out, int out_size, void* d_ws, size_t ws_size,
                              hipStream_t stream) {
    const int*   item_ids     = (const int*)d_in[0];
    const int*   basket_sizes = (const int*)d_in[1];
    const int*   lengths      = (const int*)d_in[2];
    const float* emb          = (const float*)d_in[3];
    const float* W_ih         = (const float*)d_in[4];
    const float* W_hh         = (const float*)d_in[5];
    const float* b_ih         = (const float*)d_in[6];
    const float* b_hh         = (const float*)d_in[7];
    const float* h0           = (const float*)d_in[8];
    float* out = (float*)d_out;
    float* xg  = (float*)d_ws;   // 19.7 MB
    float* ub  = out;            // reuse out_dyn region; overwritten by gru later

    gather_kernel<<<(Bn * Tn) / 8, 256, 0, stream>>>(item_ids, basket_sizes, emb, ub);
    gemm_kernel<<<1200, 256, 0, stream>>>(ub, W_ih, b_ih, xg);
    gru_kernel<<<Bn, 1024, 0, stream>>>(
        lengths, W_hh, b_hh, h0, xg, out, out + (size_t)Bn * Tn * En);
}